// Round 9
// baseline (345.012 us; speedup 1.0000x reference)
//
#include <hip/hip_runtime.h>
#include <math.h>

#define D_DIM 1024
#define H_DIM 4096
#define R_DIM 64
#define S_SP  4
#define NTOK  8192
#define CHUNK 1024   // H/S

// async global->LDS DMA: wave-uniform LDS base + lane*16 dest, per-lane src
__device__ __forceinline__ void gload_lds16(const float* g, float* l) {
  __builtin_amdgcn_global_load_lds(
      (const __attribute__((address_space(1))) unsigned int*)(unsigned long long)(uintptr_t)g,
      (__attribute__((address_space(3))) unsigned int*)(uintptr_t)l,
      16, 0, 0);
}

// ---- K0: both weight transposes in one launch ----
// blocks 0..1023:  W2(D,H) -> W2T(H,D)       (64x16 tiles of 64x64)
// blocks 1024..1087: Wc2(H,R) -> Wc2T(R,H)   (1x64 tiles)
__global__ __launch_bounds__(256) void k_transpose2(const float* __restrict__ W2,
                                                    float* __restrict__ W2T,
                                                    const float* __restrict__ Wc2,
                                                    float* __restrict__ Wc2T) {
  __shared__ float tile[64][65];
  int bid = blockIdx.x;
  const float* in;
  float* out;
  int R, C, cb, rb;
  if (bid < 1024) {
    in = W2; out = W2T; R = D_DIM; C = H_DIM;
    cb = (bid & 63) * 64; rb = (bid >> 6) * 64;
  } else {
    bid -= 1024;
    in = Wc2; out = Wc2T; R = H_DIM; C = R_DIM;
    cb = 0; rb = bid * 64;
  }
  const int tx = threadIdx.x & 63, ty = threadIdx.x >> 6;
#pragma unroll
  for (int r = 0; r < 16; ++r) {
    const int rr = ty * 16 + r;
    tile[tx][rr] = in[(size_t)(rb + rr) * C + cb + tx];
  }
  __syncthreads();
#pragma unroll
  for (int r = 0; r < 16; ++r) {
    const int cc = ty * 16 + r;
    out[(size_t)(cb + cc) * R + rb + tx] = tile[cc][tx];
  }
}

// ------- K1: chT_g[r][tok] = relu(x @ Wc1^T + bc1)^T  (64 x 8192) -------
#define C_TOK 16
__global__ __launch_bounds__(256, 4) void k_ctrl(const float* __restrict__ x,
                                                 const float* __restrict__ Wc1,
                                                 const float* __restrict__ bc1,
                                                 float* __restrict__ chT_g) {
  __shared__ float xT[64][20];   // [k][tok]
  __shared__ float wT[64][68];   // [k][r]
  const int tid = threadIdx.x;
  const int tok0 = blockIdx.x * C_TOK;
  const int lrow = tid >> 4;        // 0..15
  const int lk4  = (tid & 15) * 4;
  const int th = tid & 15;          // token
  const int r4 = (tid >> 4) * 4;    // r quad
  float acc[4] = {0.f, 0.f, 0.f, 0.f};
#pragma unroll 1
  for (int k0 = 0; k0 < D_DIM; k0 += 64) {
    __syncthreads();
    {
      const float4 v = *(const float4*)(x + (size_t)(tok0 + lrow) * D_DIM + k0 + lk4);
      xT[lk4 + 0][lrow] = v.x; xT[lk4 + 1][lrow] = v.y;
      xT[lk4 + 2][lrow] = v.z; xT[lk4 + 3][lrow] = v.w;
    }
#pragma unroll
    for (int rep = 0; rep < 4; ++rep) {
      const int row = lrow + rep * 16;
      const float4 v = *(const float4*)(Wc1 + (size_t)row * D_DIM + k0 + lk4);
      wT[lk4 + 0][row] = v.x; wT[lk4 + 1][row] = v.y;
      wT[lk4 + 2][row] = v.z; wT[lk4 + 3][row] = v.w;
    }
    __syncthreads();
#pragma unroll 8
    for (int k = 0; k < 64; ++k) {
      const float xv = xT[k][th];
      const float4 wv = *(const float4*)&wT[k][r4];
      acc[0] = fmaf(xv, wv.x, acc[0]);
      acc[1] = fmaf(xv, wv.y, acc[1]);
      acc[2] = fmaf(xv, wv.z, acc[2]);
      acc[3] = fmaf(xv, wv.w, acc[3]);
    }
  }
#pragma unroll
  for (int j = 0; j < 4; ++j) {
    const float v = acc[j] + bc1[r4 + j];
    chT_g[(size_t)(r4 + j) * NTOK + tok0 + th] = v > 0.f ? v : 0.f;
  }
}

// ---- K2a: 128tok x 128h tile, K=64 in FOUR 16-k phases, double-buffered
// DMA staging (issue next phase's global_load_lds, then compute current;
// single barrier per phase drains last iteration's prefetch, whose latency
// was hidden under a full compute phase).
#define G_TOK 128
#define G_HB  128
__global__ __launch_bounds__(256, 4) void k_gate_a(const float* __restrict__ chT_g,
                                                   const float* __restrict__ Wc2T,
                                                   const float* __restrict__ bc2,
                                                   const float* __restrict__ gumbel,
                                                   float2* __restrict__ part) {
  __shared__ float chT[2][16 * 128];
  __shared__ float wT[2][16 * 128];
  const int tid = threadIdx.x;
  const int tok0 = blockIdx.x * G_TOK;
  const int hb = blockIdx.y;           // 0..7
  const int s  = blockIdx.z;           // 0..3
  const int h0 = hb * G_HB;
  const int w    = tid >> 6;           // wave 0..3
  const int lane = tid & 63;
  const int lsub = lane >> 5;          // 0/1 (row within 2-row DMA)
  const int lcol = (lane & 31) * 4;
  const int th  = tid & 15;
  const int tt8 = (tid >> 4) * 8;
  const int th4 = th * 4;

  const float* csrc0 = chT_g + (size_t)tok0;
  const float* wsrc0 = Wc2T + (size_t)(s * CHUNK + h0);

#define STAGE(P, BUF) do {                                                    \
    _Pragma("unroll")                                                         \
    for (int j = 0; j < 2; ++j) {                                             \
      const int rp = w * 4 + j * 2;          /* 2-row pair base, 0..14 */     \
      const int row = (P) * 16 + rp + lsub;  /* global k row */               \
      gload_lds16(csrc0 + (size_t)row * NTOK + lcol, &chT[BUF][rp * 128]);    \
      gload_lds16(wsrc0 + (size_t)row * H_DIM + lcol, &wT[BUF][rp * 128]);    \
    }                                                                         \
  } while (0)

  float acc[8][8];
#pragma unroll
  for (int i = 0; i < 8; ++i)
#pragma unroll
    for (int j = 0; j < 8; ++j) acc[i][j] = 0.f;

  STAGE(0, 0);
#pragma unroll 1
  for (int p = 0; p < 4; ++p) {
    __syncthreads();                       // drains prev prefetch (hidden)
    if (p < 3) {
      if ((p & 1) == 0) STAGE(p + 1, 1); else STAGE(p + 1, 0);
    }
    __builtin_amdgcn_sched_barrier(0);
    const float* cb = &chT[p & 1][0];
    const float* wb = &wT[p & 1][0];
#pragma unroll
    for (int k = 0; k < 16; ++k) {
      const float4 c0 = *(const float4*)&cb[k * 128 + tt8];
      const float4 c1 = *(const float4*)&cb[k * 128 + tt8 + 4];
      const float4 w0 = *(const float4*)&wb[k * 128 + th4];
      const float4 w1 = *(const float4*)&wb[k * 128 + 64 + th4];
      const float ca[8] = {c0.x, c0.y, c0.z, c0.w, c1.x, c1.y, c1.z, c1.w};
      const float wa[8] = {w0.x, w0.y, w0.z, w0.w, w1.x, w1.y, w1.z, w1.w};
#pragma unroll
      for (int i = 0; i < 8; ++i)
#pragma unroll
        for (int j = 0; j < 8; ++j) acc[i][j] = fmaf(ca[i], wa[j], acc[i][j]);
    }
  }
#undef STAGE

  // epilogue: + bias + gumbel, per-token partial argmax over this 128-h tile
  const float4 b0 = *(const float4*)(bc2 + s * CHUNK + h0 + th4);
  const float4 b1 = *(const float4*)(bc2 + s * CHUNK + h0 + 64 + th4);
  const float ba[8] = {b0.x, b0.y, b0.z, b0.w, b1.x, b1.y, b1.z, b1.w};
#pragma unroll
  for (int i = 0; i < 8; ++i) {
    const int tok = tok0 + tt8 + i;
    const float* gp = gumbel + ((size_t)tok * S_SP + s) * CHUNK + h0;
    const float4 g0 = *(const float4*)(gp + th4);
    const float4 g1 = *(const float4*)(gp + 64 + th4);
    const float ga[8] = {g0.x, g0.y, g0.z, g0.w, g1.x, g1.y, g1.z, g1.w};
    float bv = -INFINITY; int bi = 0;
#pragma unroll
    for (int j = 0; j < 8; ++j) {
      const int hl = (j < 4) ? (th4 + j) : (64 + th4 + j - 4);
      const float val = acc[i][j] + ba[j] + ga[j];
      if (val > bv) { bv = val; bi = hl; }   // ascending hl within thread
    }
#pragma unroll
    for (int o = 8; o > 0; o >>= 1) {
      const float ov = __shfl_down(bv, o, 16);
      const int   oi = __shfl_down(bi, o, 16);
      if (ov > bv || (ov == bv && oi < bi)) { bv = ov; bi = oi; }
    }
    if (th == 0)
      part[((size_t)tok * S_SP + s) * 8 + hb] = make_float2(bv, __int_as_float(h0 + bi));
  }
}

// ------- K3: wave-per-token sparse FFN; folds the partial-argmax reduce ---
__global__ __launch_bounds__(256) void k_ffn(const float* __restrict__ x,
                                             const float* __restrict__ W1,
                                             const float* __restrict__ b1,
                                             const float* __restrict__ W2T,
                                             const float* __restrict__ b2,
                                             const float2* __restrict__ part,
                                             float* __restrict__ out) {
  const int tid  = threadIdx.x;
  const int lane = tid & 63;
  const int wv   = tid >> 6;
  const int token = blockIdx.x * 4 + wv;
  float bv = -INFINITY; int bi = 0;
  {
    const int ss = (lane >> 3) & 3;
    const int q  = lane & 7;
    if (lane < 32) {
      const float2 p = part[((size_t)token * S_SP + ss) * 8 + q];
      bv = p.x; bi = __float_as_int(p.y);
    }
#pragma unroll
    for (int o = 4; o > 0; o >>= 1) {
      const float ov = __shfl_down(bv, o, 8);
      const int   oi = __shfl_down(bi, o, 8);
      if (ov > bv || (ov == bv && oi < bi)) { bv = ov; bi = oi; }
    }
  }
  int h[4];
#pragma unroll
  for (int s2 = 0; s2 < 4; ++s2)
    h[s2] = s2 * CHUNK + __shfl(bi, s2 * 8);

  const int d0 = lane * 16;
  const float* xp = x + (size_t)token * D_DIM + d0;
  const float4 x0 = *(const float4*)(xp + 0);
  const float4 x1 = *(const float4*)(xp + 4);
  const float4 x2 = *(const float4*)(xp + 8);
  const float4 x3 = *(const float4*)(xp + 12);
  float p[4];
#pragma unroll
  for (int s2 = 0; s2 < 4; ++s2) {
    const float* wr = W1 + (size_t)h[s2] * D_DIM + d0;
    const float4 a0 = *(const float4*)(wr + 0);
    const float4 a1 = *(const float4*)(wr + 4);
    const float4 a2 = *(const float4*)(wr + 8);
    const float4 a3 = *(const float4*)(wr + 12);
    float v = 0.f;
    v = fmaf(x0.x, a0.x, v); v = fmaf(x0.y, a0.y, v);
    v = fmaf(x0.z, a0.z, v); v = fmaf(x0.w, a0.w, v);
    v = fmaf(x1.x, a1.x, v); v = fmaf(x1.y, a1.y, v);
    v = fmaf(x1.z, a1.z, v); v = fmaf(x1.w, a1.w, v);
    v = fmaf(x2.x, a2.x, v); v = fmaf(x2.y, a2.y, v);
    v = fmaf(x2.z, a2.z, v); v = fmaf(x2.w, a2.w, v);
    v = fmaf(x3.x, a3.x, v); v = fmaf(x3.y, a3.y, v);
    v = fmaf(x3.z, a3.z, v); v = fmaf(x3.w, a3.w, v);
    p[s2] = v;
  }
#pragma unroll
  for (int s2 = 0; s2 < 4; ++s2) {
#pragma unroll
    for (int o = 1; o < 64; o <<= 1) p[s2] += __shfl_xor(p[s2], o);
  }
  float hvv[4];
#pragma unroll
  for (int s2 = 0; s2 < 4; ++s2) {
    const float v = p[s2] + b1[h[s2]];
    hvv[s2] = v > 0.f ? v : 0.f;
  }
  float4 o0 = *(const float4*)(b2 + d0 + 0);
  float4 o1 = *(const float4*)(b2 + d0 + 4);
  float4 o2 = *(const float4*)(b2 + d0 + 8);
  float4 o3 = *(const float4*)(b2 + d0 + 12);
#pragma unroll
  for (int s2 = 0; s2 < 4; ++s2) {
    const float* wr = W2T + (size_t)h[s2] * D_DIM + d0;
    const float4 a0 = *(const float4*)(wr + 0);
    const float4 a1 = *(const float4*)(wr + 4);
    const float4 a2 = *(const float4*)(wr + 8);
    const float4 a3 = *(const float4*)(wr + 12);
    const float g = hvv[s2];
    o0.x = fmaf(g, a0.x, o0.x); o0.y = fmaf(g, a0.y, o0.y);
    o0.z = fmaf(g, a0.z, o0.z); o0.w = fmaf(g, a0.w, o0.w);
    o1.x = fmaf(g, a1.x, o1.x); o1.y = fmaf(g, a1.y, o1.y);
    o1.z = fmaf(g, a1.z, o1.z); o1.w = fmaf(g, a1.w, o1.w);
    o2.x = fmaf(g, a2.x, o2.x); o2.y = fmaf(g, a2.y, o2.y);
    o2.z = fmaf(g, a2.z, o2.z); o2.w = fmaf(g, a2.w, o2.w);
    o3.x = fmaf(g, a3.x, o3.x); o3.y = fmaf(g, a3.y, o3.y);
    o3.z = fmaf(g, a3.z, o3.z); o3.w = fmaf(g, a3.w, o3.w);
  }
  float* op = out + (size_t)token * D_DIM + d0;
  *(float4*)(op + 0)  = o0;
  *(float4*)(op + 4)  = o1;
  *(float4*)(op + 8)  = o2;
  *(float4*)(op + 12) = o3;
}

extern "C" void kernel_launch(void* const* d_in, const int* in_sizes, int n_in,
                              void* d_out, int out_size, void* d_ws, size_t ws_size,
                              hipStream_t stream) {
  const float* x      = (const float*)d_in[0];
  const float* W1     = (const float*)d_in[1];
  const float* b1     = (const float*)d_in[2];
  const float* W2     = (const float*)d_in[3];
  const float* b2     = (const float*)d_in[4];
  const float* Wc1    = (const float*)d_in[5];
  const float* bc1    = (const float*)d_in[6];
  const float* Wc2    = (const float*)d_in[7];
  const float* bc2    = (const float*)d_in[8];
  const float* gumbel = (const float*)d_in[9];
  float* out = (float*)d_out;

  char* ws = (char*)d_ws;
  float*  W2T   = (float*)ws;                                   // 16.78 MB
  float*  chT_g = (float*)(ws + 16777216);                      //  2.10 MB
  float2* part  = (float2*)(ws + 16777216 + 2097152);           //  2.10 MB
  float*  Wc2T  = (float*)(ws + 16777216 + 2097152 + 2097152);  //  1.05 MB

  hipLaunchKernelGGL(k_transpose2, dim3(1024 + 64), dim3(256), 0, stream,
                     W2, W2T, Wc2, Wc2T);
  hipLaunchKernelGGL(k_ctrl, dim3(NTOK / C_TOK), dim3(256), 0, stream,
                     x, Wc1, bc1, chT_g);
  hipLaunchKernelGGL(k_gate_a, dim3(NTOK / G_TOK, CHUNK / G_HB, S_SP), dim3(256), 0, stream,
                     chT_g, Wc2T, bc2, gumbel, part);
  hipLaunchKernelGGL(k_ffn, dim3(NTOK / 4), dim3(256), 0, stream,
                     x, W1, b1, W2T, b2, part, out);
}

// Round 10
// 187.379 us; speedup vs baseline: 1.8413x; 1.8413x over previous
//
#include <hip/hip_runtime.h>
#include <math.h>

#define D_DIM 1024
#define H_DIM 4096
#define R_DIM 64
#define S_SP  4
#define NTOK  8192
#define CHUNK 1024   // H/S

// async global->LDS DMA: wave-uniform LDS base + lane*16 dest, per-lane src
__device__ __forceinline__ void gload_lds16(const float* g, float* l) {
  __builtin_amdgcn_global_load_lds(
      (const __attribute__((address_space(1))) unsigned int*)(unsigned long long)(uintptr_t)g,
      (__attribute__((address_space(3))) unsigned int*)(uintptr_t)l,
      16, 0, 0);
}

// ---- K_A: fused {W2 transpose | Wc2 transpose | ctrl GEMM} ----
// bid <1024: W2(D,H)->W2T(H,D); 1024..1087: Wc2(H,R)->Wc2T(R,H);
// 1088..1599: ch controller GEMM block.
#define C_TOK 16
__global__ __launch_bounds__(256, 4) void k_fusedA(const float* __restrict__ W2,
                                                   float* __restrict__ W2T,
                                                   const float* __restrict__ Wc2,
                                                   float* __restrict__ Wc2T,
                                                   const float* __restrict__ x,
                                                   const float* __restrict__ Wc1,
                                                   const float* __restrict__ bc1,
                                                   float* __restrict__ chT_g) {
  __shared__ float smem[64 * 68 + 64 * 20];   // max(transpose 64*65, ctrl tiles)
  int bid = blockIdx.x;
  const int tid = threadIdx.x;
  if (bid < 1088) {
    // ---- transpose path ----
    float (*tile)[65] = (float (*)[65])smem;
    const float* in; float* out; int R, C, cb, rb;
    if (bid < 1024) {
      in = W2; out = W2T; R = D_DIM; C = H_DIM;
      cb = (bid & 63) * 64; rb = (bid >> 6) * 64;
    } else {
      bid -= 1024;
      in = Wc2; out = Wc2T; R = H_DIM; C = R_DIM;
      cb = 0; rb = bid * 64;
    }
    const int tx = tid & 63, ty = tid >> 6;
#pragma unroll
    for (int r = 0; r < 16; ++r) {
      const int rr = ty * 16 + r;
      tile[tx][rr] = in[(size_t)(rb + rr) * C + cb + tx];
    }
    __syncthreads();
#pragma unroll
    for (int r = 0; r < 16; ++r) {
      const int cc = ty * 16 + r;
      out[(size_t)(cb + cc) * R + rb + tx] = tile[cc][tx];
    }
    return;
  }
  // ---- ctrl path: chT_g[r][tok] = relu(x @ Wc1^T + bc1)^T ----
  float (*wT)[68] = (float (*)[68])smem;               // [k][r]
  float (*xT)[20] = (float (*)[20])(smem + 64 * 68);   // [k][tok]
  const int tok0 = (bid - 1088) * C_TOK;
  const int lrow = tid >> 4;        // 0..15
  const int lk4  = (tid & 15) * 4;
  const int th = tid & 15;          // token
  const int r4 = (tid >> 4) * 4;    // r quad
  float acc[4] = {0.f, 0.f, 0.f, 0.f};
#pragma unroll 1
  for (int k0 = 0; k0 < D_DIM; k0 += 64) {
    __syncthreads();
    {
      const float4 v = *(const float4*)(x + (size_t)(tok0 + lrow) * D_DIM + k0 + lk4);
      xT[lk4 + 0][lrow] = v.x; xT[lk4 + 1][lrow] = v.y;
      xT[lk4 + 2][lrow] = v.z; xT[lk4 + 3][lrow] = v.w;
    }
#pragma unroll
    for (int rep = 0; rep < 4; ++rep) {
      const int row = lrow + rep * 16;
      const float4 v = *(const float4*)(Wc1 + (size_t)row * D_DIM + k0 + lk4);
      wT[lk4 + 0][row] = v.x; wT[lk4 + 1][row] = v.y;
      wT[lk4 + 2][row] = v.z; wT[lk4 + 3][row] = v.w;
    }
    __syncthreads();
#pragma unroll 8
    for (int k = 0; k < 64; ++k) {
      const float xv = xT[k][th];
      const float4 wv = *(const float4*)&wT[k][r4];
      acc[0] = fmaf(xv, wv.x, acc[0]);
      acc[1] = fmaf(xv, wv.y, acc[1]);
      acc[2] = fmaf(xv, wv.z, acc[2]);
      acc[3] = fmaf(xv, wv.w, acc[3]);
    }
  }
#pragma unroll
  for (int j = 0; j < 4; ++j) {
    const float v = acc[j] + bc1[r4 + j];
    chT_g[(size_t)(r4 + j) * NTOK + tok0 + th] = v > 0.f ? v : 0.f;
  }
}

#define G_TOK 128
#define G_HB  128

// shared epilogue: + bias + gumbel, per-token partial argmax over 128-h tile
#define GATE_EPILOGUE                                                         \
  const float4 b0 = *(const float4*)(bc2 + s * CHUNK + h0 + th4);             \
  const float4 b1 = *(const float4*)(bc2 + s * CHUNK + h0 + 64 + th4);        \
  const float ba[8] = {b0.x, b0.y, b0.z, b0.w, b1.x, b1.y, b1.z, b1.w};       \
  _Pragma("unroll")                                                           \
  for (int i = 0; i < 8; ++i) {                                               \
    const int tok = tok0 + tt8 + i;                                           \
    const float* gp = gumbel + ((size_t)tok * S_SP + s) * CHUNK + h0;         \
    const float4 g0 = *(const float4*)(gp + th4);                             \
    const float4 g1 = *(const float4*)(gp + 64 + th4);                        \
    const float ga[8] = {g0.x, g0.y, g0.z, g0.w, g1.x, g1.y, g1.z, g1.w};     \
    float bv = -INFINITY; int bi = 0;                                         \
    _Pragma("unroll")                                                         \
    for (int j = 0; j < 8; ++j) {                                             \
      const int hl = (j < 4) ? (th4 + j) : (64 + th4 + j - 4);                \
      const float val = acc[i][j] + ba[j] + ga[j];                            \
      if (val > bv) { bv = val; bi = hl; }                                    \
    }                                                                         \
    _Pragma("unroll")                                                         \
    for (int o = 8; o > 0; o >>= 1) {                                         \
      const float ov = __shfl_down(bv, o, 16);                                \
      const int   oi = __shfl_down(bi, o, 16);                                \
      if (ov > bv || (ov == bv && oi < bi)) { bv = ov; bi = oi; }             \
    }                                                                         \
    if (th == 0)                                                              \
      part[((size_t)tok * S_SP + s) * 8 + hb] =                               \
          make_float2(bv, __int_as_float(h0 + bi));                           \
  }

// ---- K2a variant A: 2-phase K=32 staging (exact R8 structure) ----
__global__ __launch_bounds__(256, 4) void k_gate_a2(const float* __restrict__ chT_g,
                                                    const float* __restrict__ Wc2T,
                                                    const float* __restrict__ bc2,
                                                    const float* __restrict__ gumbel,
                                                    float2* __restrict__ part,
                                                    int s_base) {
  __shared__ float chT[32 * 128];
  __shared__ float wT[32 * 128];
  const int tid = threadIdx.x;
  const int tok0 = blockIdx.x * G_TOK;
  const int hb = blockIdx.y;
  const int s  = blockIdx.z + s_base;
  const int h0 = hb * G_HB;
  const int w    = tid >> 6;
  const int lane = tid & 63;
  const int lsub = lane >> 5;
  const int lcol = (lane & 31) * 4;
  const int th  = tid & 15;
  const int tt8 = (tid >> 4) * 8;
  const int th4 = th * 4;
  float acc[8][8];
#pragma unroll
  for (int i = 0; i < 8; ++i)
#pragma unroll
    for (int j = 0; j < 8; ++j) acc[i][j] = 0.f;

#pragma unroll 1
  for (int p = 0; p < 2; ++p) {
    __syncthreads();
#pragma unroll
    for (int j = 0; j < 4; ++j) {
      const int krow = 8 * w + 2 * j + lsub;
      gload_lds16(chT_g + (size_t)(p * 32 + krow) * NTOK + tok0 + lcol,
                  &chT[(8 * w + 2 * j) * 128]);
      gload_lds16(Wc2T + (size_t)(p * 32 + krow) * H_DIM + s * CHUNK + h0 + lcol,
                  &wT[(8 * w + 2 * j) * 128]);
    }
    __syncthreads();
#pragma unroll 8
    for (int k = 0; k < 32; ++k) {
      const float4 c0 = *(const float4*)&chT[k * 128 + tt8];
      const float4 c1 = *(const float4*)&chT[k * 128 + tt8 + 4];
      const float4 w0 = *(const float4*)&wT[k * 128 + th4];
      const float4 w1 = *(const float4*)&wT[k * 128 + 64 + th4];
      const float ca[8] = {c0.x, c0.y, c0.z, c0.w, c1.x, c1.y, c1.z, c1.w};
      const float wa[8] = {w0.x, w0.y, w0.z, w0.w, w1.x, w1.y, w1.z, w1.w};
#pragma unroll
      for (int i = 0; i < 8; ++i)
#pragma unroll
        for (int j = 0; j < 8; ++j) acc[i][j] = fmaf(ca[i], wa[j], acc[i][j]);
    }
  }
  GATE_EPILOGUE
}

// ---- K2a variant B: 1-phase K=64 staging (64KB LDS, one barrier pair) ----
__global__ __launch_bounds__(256, 2) void k_gate_a1(const float* __restrict__ chT_g,
                                                    const float* __restrict__ Wc2T,
                                                    const float* __restrict__ bc2,
                                                    const float* __restrict__ gumbel,
                                                    float2* __restrict__ part,
                                                    int s_base) {
  __shared__ float chT[64 * 128];
  __shared__ float wT[64 * 128];
  const int tid = threadIdx.x;
  const int tok0 = blockIdx.x * G_TOK;
  const int hb = blockIdx.y;
  const int s  = blockIdx.z + s_base;
  const int h0 = hb * G_HB;
  const int w    = tid >> 6;
  const int lane = tid & 63;
  const int lsub = lane >> 5;
  const int lcol = (lane & 31) * 4;
  const int th  = tid & 15;
  const int tt8 = (tid >> 4) * 8;
  const int th4 = th * 4;
  float acc[8][8];
#pragma unroll
  for (int i = 0; i < 8; ++i)
#pragma unroll
    for (int j = 0; j < 8; ++j) acc[i][j] = 0.f;

  // stage all 64 k rows: wave w owns rows [w*16, w*16+16)
#pragma unroll
  for (int j = 0; j < 8; ++j) {
    const int rp = w * 16 + j * 2;
    const int row = rp + lsub;
    gload_lds16(chT_g + (size_t)row * NTOK + tok0 + lcol, &chT[rp * 128]);
    gload_lds16(Wc2T + (size_t)row * H_DIM + s * CHUNK + h0 + lcol, &wT[rp * 128]);
  }
  __syncthreads();
#pragma unroll 8
  for (int k = 0; k < 64; ++k) {
    const float4 c0 = *(const float4*)&chT[k * 128 + tt8];
    const float4 c1 = *(const float4*)&chT[k * 128 + tt8 + 4];
    const float4 w0 = *(const float4*)&wT[k * 128 + th4];
    const float4 w1 = *(const float4*)&wT[k * 128 + 64 + th4];
    const float ca[8] = {c0.x, c0.y, c0.z, c0.w, c1.x, c1.y, c1.z, c1.w};
    const float wa[8] = {w0.x, w0.y, w0.z, w0.w, w1.x, w1.y, w1.z, w1.w};
#pragma unroll
    for (int i = 0; i < 8; ++i)
#pragma unroll
      for (int j = 0; j < 8; ++j) acc[i][j] = fmaf(ca[i], wa[j], acc[i][j]);
  }
  GATE_EPILOGUE
}

// ------- K3: wave-per-token sparse FFN; folds the partial-argmax reduce ---
__global__ __launch_bounds__(256) void k_ffn(const float* __restrict__ x,
                                             const float* __restrict__ W1,
                                             const float* __restrict__ b1,
                                             const float* __restrict__ W2T,
                                             const float* __restrict__ b2,
                                             const float2* __restrict__ part,
                                             float* __restrict__ out) {
  const int tid  = threadIdx.x;
  const int lane = tid & 63;
  const int wv   = tid >> 6;
  const int token = blockIdx.x * 4 + wv;
  float bv = -INFINITY; int bi = 0;
  {
    const int ss = (lane >> 3) & 3;
    const int q  = lane & 7;
    if (lane < 32) {
      const float2 p = part[((size_t)token * S_SP + ss) * 8 + q];
      bv = p.x; bi = __float_as_int(p.y);
    }
#pragma unroll
    for (int o = 4; o > 0; o >>= 1) {
      const float ov = __shfl_down(bv, o, 8);
      const int   oi = __shfl_down(bi, o, 8);
      if (ov > bv || (ov == bv && oi < bi)) { bv = ov; bi = oi; }
    }
  }
  int h[4];
#pragma unroll
  for (int s2 = 0; s2 < 4; ++s2)
    h[s2] = s2 * CHUNK + __shfl(bi, s2 * 8);

  const int d0 = lane * 16;
  const float* xp = x + (size_t)token * D_DIM + d0;
  const float4 x0 = *(const float4*)(xp + 0);
  const float4 x1 = *(const float4*)(xp + 4);
  const float4 x2 = *(const float4*)(xp + 8);
  const float4 x3 = *(const float4*)(xp + 12);
  float p[4];
#pragma unroll
  for (int s2 = 0; s2 < 4; ++s2) {
    const float* wr = W1 + (size_t)h[s2] * D_DIM + d0;
    const float4 a0 = *(const float4*)(wr + 0);
    const float4 a1 = *(const float4*)(wr + 4);
    const float4 a2 = *(const float4*)(wr + 8);
    const float4 a3 = *(const float4*)(wr + 12);
    float v = 0.f;
    v = fmaf(x0.x, a0.x, v); v = fmaf(x0.y, a0.y, v);
    v = fmaf(x0.z, a0.z, v); v = fmaf(x0.w, a0.w, v);
    v = fmaf(x1.x, a1.x, v); v = fmaf(x1.y, a1.y, v);
    v = fmaf(x1.z, a1.z, v); v = fmaf(x1.w, a1.w, v);
    v = fmaf(x2.x, a2.x, v); v = fmaf(x2.y, a2.y, v);
    v = fmaf(x2.z, a2.z, v); v = fmaf(x2.w, a2.w, v);
    v = fmaf(x3.x, a3.x, v); v = fmaf(x3.y, a3.y, v);
    v = fmaf(x3.z, a3.z, v); v = fmaf(x3.w, a3.w, v);
    p[s2] = v;
  }
#pragma unroll
  for (int s2 = 0; s2 < 4; ++s2) {
#pragma unroll
    for (int o = 1; o < 64; o <<= 1) p[s2] += __shfl_xor(p[s2], o);
  }
  float hvv[4];
#pragma unroll
  for (int s2 = 0; s2 < 4; ++s2) {
    const float v = p[s2] + b1[h[s2]];
    hvv[s2] = v > 0.f ? v : 0.f;
  }
  float4 o0 = *(const float4*)(b2 + d0 + 0);
  float4 o1 = *(const float4*)(b2 + d0 + 4);
  float4 o2 = *(const float4*)(b2 + d0 + 8);
  float4 o3 = *(const float4*)(b2 + d0 + 12);
#pragma unroll
  for (int s2 = 0; s2 < 4; ++s2) {
    const float* wr = W2T + (size_t)h[s2] * D_DIM + d0;
    const float4 a0 = *(const float4*)(wr + 0);
    const float4 a1 = *(const float4*)(wr + 4);
    const float4 a2 = *(const float4*)(wr + 8);
    const float4 a3 = *(const float4*)(wr + 12);
    const float g = hvv[s2];
    o0.x = fmaf(g, a0.x, o0.x); o0.y = fmaf(g, a0.y, o0.y);
    o0.z = fmaf(g, a0.z, o0.z); o0.w = fmaf(g, a0.w, o0.w);
    o1.x = fmaf(g, a1.x, o1.x); o1.y = fmaf(g, a1.y, o1.y);
    o1.z = fmaf(g, a1.z, o1.z); o1.w = fmaf(g, a1.w, o1.w);
    o2.x = fmaf(g, a2.x, o2.x); o2.y = fmaf(g, a2.y, o2.y);
    o2.z = fmaf(g, a2.z, o2.z); o2.w = fmaf(g, a2.w, o2.w);
    o3.x = fmaf(g, a3.x, o3.x); o3.y = fmaf(g, a3.y, o3.y);
    o3.z = fmaf(g, a3.z, o3.z); o3.w = fmaf(g, a3.w, o3.w);
  }
  float* op = out + (size_t)token * D_DIM + d0;
  *(float4*)(op + 0)  = o0;
  *(float4*)(op + 4)  = o1;
  *(float4*)(op + 8)  = o2;
  *(float4*)(op + 12) = o3;
}

extern "C" void kernel_launch(void* const* d_in, const int* in_sizes, int n_in,
                              void* d_out, int out_size, void* d_ws, size_t ws_size,
                              hipStream_t stream) {
  const float* x      = (const float*)d_in[0];
  const float* W1     = (const float*)d_in[1];
  const float* b1     = (const float*)d_in[2];
  const float* W2     = (const float*)d_in[3];
  const float* b2     = (const float*)d_in[4];
  const float* Wc1    = (const float*)d_in[5];
  const float* bc1    = (const float*)d_in[6];
  const float* Wc2    = (const float*)d_in[7];
  const float* bc2    = (const float*)d_in[8];
  const float* gumbel = (const float*)d_in[9];
  float* out = (float*)d_out;

  char* ws = (char*)d_ws;
  float*  W2T   = (float*)ws;                                   // 16.78 MB
  float*  chT_g = (float*)(ws + 16777216);                      //  2.10 MB
  float2* part  = (float2*)(ws + 16777216 + 2097152);           //  2.10 MB
  float*  Wc2T  = (float*)(ws + 16777216 + 2097152 + 2097152);  //  1.05 MB

  hipLaunchKernelGGL(k_fusedA, dim3(1088 + NTOK / C_TOK), dim3(256), 0, stream,
                     W2, W2T, Wc2, Wc2T, x, Wc1, bc1, chT_g);
  // within-probe A/B: s=0,1 via 2-phase (R8), s=2,3 via 1-phase
  hipLaunchKernelGGL(k_gate_a2, dim3(NTOK / G_TOK, CHUNK / G_HB, 2), dim3(256), 0, stream,
                     chT_g, Wc2T, bc2, gumbel, part, 0);
  hipLaunchKernelGGL(k_gate_a1, dim3(NTOK / G_TOK, CHUNK / G_HB, 2), dim3(256), 0, stream,
                     chT_g, Wc2T, bc2, gumbel, part, 2);
  hipLaunchKernelGGL(k_ffn, dim3(NTOK / 4), dim3(256), 0, stream,
                     x, W1, b1, W2T, b2, part, out);
}